// Round 7
// baseline (421.200 us; speedup 1.0000x reference)
//
#include <hip/hip_runtime.h>
#include <math.h>

typedef short s8 __attribute__((ext_vector_type(8)));   // 8 bf16 in 4 VGPRs
typedef float f4 __attribute__((ext_vector_type(4)));   // MFMA 16x16 acc
typedef unsigned short ushort_t;

__device__ __forceinline__ float fexp2f(float x) { return __builtin_amdgcn_exp2f(x); }
__device__ __forceinline__ float frcpf(float x)  { return __builtin_amdgcn_rcpf(x); }
__device__ __forceinline__ float sigf(float x) {
    return frcpf(1.f + fexp2f(x * -1.44269504f));
}
__device__ __forceinline__ float tanh_f(float x) {
    float e = fexp2f(x * 2.88539008f);
    return 1.f - 2.f * frcpf(e + 1.f);
}
__device__ __forceinline__ ushort_t f2b(float f) {
    unsigned u = __float_as_uint(f);
    u = (u + 0x7FFF + ((u >> 16) & 1)) >> 16;   // RNE
    return (ushort_t)u;
}
__device__ __forceinline__ float b2f(ushort_t b) {
    return __uint_as_float(((unsigned)b) << 16);
}

// ---------------------------------------------------------------------------
// Convert emb / Wih / Whh / SW^T to bf16 + zero grid-barrier counters.
// ---------------------------------------------------------------------------
#define EMB_N   6400000          // 50000*128
#define W_N     49152            // 384*128
#define SW_N    16384            // 128*128
#define CVT_N   (EMB_N + 2 * W_N + SW_N)

__global__ __launch_bounds__(256) void cvt_kernel(
    const float* __restrict__ emb, const float* __restrict__ wih,
    const float* __restrict__ whh, const float* __restrict__ sw,
    ushort_t* __restrict__ embb, ushort_t* __restrict__ wihb,
    ushort_t* __restrict__ whhb, ushort_t* __restrict__ swtb,
    unsigned* __restrict__ bar)
{
    if (blockIdx.x == 0 && threadIdx.x < 8) bar[threadIdx.x] = 0;
    int i = (blockIdx.x * 256 + threadIdx.x) * 4;
    if (i >= CVT_N) return;
    if (i < EMB_N) {
        float4 v = *(const float4*)(emb + i);
        short4 o; o.x = f2b(v.x); o.y = f2b(v.y); o.z = f2b(v.z); o.w = f2b(v.w);
        *(short4*)(embb + i) = o;
    } else if (i < EMB_N + W_N) {
        int j = i - EMB_N;
        float4 v = *(const float4*)(wih + j);
        short4 o; o.x = f2b(v.x); o.y = f2b(v.y); o.z = f2b(v.z); o.w = f2b(v.w);
        *(short4*)(wihb + j) = o;
    } else if (i < EMB_N + 2 * W_N) {
        int j = i - EMB_N - W_N;
        float4 v = *(const float4*)(whh + j);
        short4 o; o.x = f2b(v.x); o.y = f2b(v.y); o.z = f2b(v.z); o.w = f2b(v.w);
        *(short4*)(whhb + j) = o;
    } else {
        int j = i - EMB_N - 2 * W_N;
        int f = j >> 7, e0 = j & 127;
        short4 o;
        o.x = f2b(sw[(e0 + 0) * 128 + f]);
        o.y = f2b(sw[(e0 + 1) * 128 + f]);
        o.z = f2b(sw[(e0 + 2) * 128 + f]);
        o.w = f2b(sw[(e0 + 3) * 128 + f]);
        *(short4*)(swtb + j) = o;        // SWt[f][e]
    }
}

// ---------------------------------------------------------------------------
// GRU step (round-4 structure: best measured throughput). Block = 512 thr,
// 128 rows (8 M-tiles); wave w owns gate cols w*16..+15; operand-swapped MFMA.
// ---------------------------------------------------------------------------
template <bool HAS_H0>
__global__ __launch_bounds__(512, 2) void gru_mfma(
    const int* __restrict__ tokens, const ushort_t* __restrict__ embb,
    const ushort_t* __restrict__ wihb, const ushort_t* __restrict__ whhb,
    const float* __restrict__ bih, const float* __restrict__ bhh,
    const ushort_t* __restrict__ h0buf, ushort_t* __restrict__ hbuf,
    int lvl_start)
{
    __shared__ ushort_t xs[128 * 136];
    __shared__ ushort_t hs[HAS_H0 ? 128 * 136 : 8];

    const int t = threadIdx.x;
    const int base = blockIdx.x * 128;

    {
        int rl = t >> 2, c0 = (t & 3) * 32;
        int row = base + rl;
        int tok = tokens[(lvl_start + (row >> 8)) * 256 + (row & 255)];
        const ushort_t* src = embb + (size_t)tok * 128 + c0;
        ushort_t* dst = &xs[rl * 136 + c0];
        #pragma unroll
        for (int i = 0; i < 4; ++i) *(s8*)(dst + 8 * i) = *(const s8*)(src + 8 * i);
        if (HAS_H0) {
            const ushort_t* hsrc = h0buf + (size_t)row * 128 + c0;
            ushort_t* hdst = &hs[rl * 136 + c0];
            #pragma unroll
            for (int i = 0; i < 4; ++i) *(s8*)(hdst + 8 * i) = *(const s8*)(hsrc + 8 * i);
        }
    }

    const int lane = t & 63, w = t >> 6;
    const int quad = lane >> 4, l15 = lane & 15;
    const int gA = w * 16 + l15;
    const int g0 = w * 16 + quad * 4;

    s8 bwi[3][4], bwh[3][4];
    #pragma unroll
    for (int gm = 0; gm < 3; ++gm) {
        const ushort_t* wp = wihb + (size_t)(gm * 128 + gA) * 128 + quad * 8;
        #pragma unroll
        for (int s = 0; s < 4; ++s) bwi[gm][s] = *(const s8*)(wp + 32 * s);
    }
    if (HAS_H0) {
        #pragma unroll
        for (int gm = 0; gm < 3; ++gm) {
            const ushort_t* wp = whhb + (size_t)(gm * 128 + gA) * 128 + quad * 8;
            #pragma unroll
            for (int s = 0; s < 4; ++s) bwh[gm][s] = *(const s8*)(wp + 32 * s);
        }
    }

    float bR[4], bZ[4], biN[4], bhN[4];
    {
        float4 a = *(const float4*)(bih + g0);
        float4 b = *(const float4*)(bhh + g0);
        bR[0] = a.x + b.x; bR[1] = a.y + b.y; bR[2] = a.z + b.z; bR[3] = a.w + b.w;
        float4 c = *(const float4*)(bih + 128 + g0);
        float4 d = *(const float4*)(bhh + 128 + g0);
        bZ[0] = c.x + d.x; bZ[1] = c.y + d.y; bZ[2] = c.z + d.z; bZ[3] = c.w + d.w;
        float4 e = *(const float4*)(bih + 256 + g0);
        float4 f = *(const float4*)(bhh + 256 + g0);
        biN[0] = e.x; biN[1] = e.y; biN[2] = e.z; biN[3] = e.w;
        bhN[0] = f.x; bhN[1] = f.y; bhN[2] = f.z; bhN[3] = f.w;
    }

    __syncthreads();

    #pragma unroll 1
    for (int mt = 0; mt < 8; ++mt) {
        const int row = mt * 16 + l15;
        s8 ax[4], ah[4];
        {
            const ushort_t* ap = &xs[row * 136 + quad * 8];
            #pragma unroll
            for (int s = 0; s < 4; ++s) ax[s] = *(const s8*)(ap + 32 * s);
            if (HAS_H0) {
                const ushort_t* hp = &hs[row * 136 + quad * 8];
                #pragma unroll
                for (int s = 0; s < 4; ++s) ah[s] = *(const s8*)(hp + 32 * s);
            }
        }

        f4 accR = (f4)0.f, accZ = (f4)0.f, accN = (f4)0.f, accNh = (f4)0.f;
        #pragma unroll
        for (int s = 0; s < 4; ++s) {
            accR = __builtin_amdgcn_mfma_f32_16x16x32_bf16(bwi[0][s], ax[s], accR, 0, 0, 0);
            accZ = __builtin_amdgcn_mfma_f32_16x16x32_bf16(bwi[1][s], ax[s], accZ, 0, 0, 0);
            accN = __builtin_amdgcn_mfma_f32_16x16x32_bf16(bwi[2][s], ax[s], accN, 0, 0, 0);
        }
        if (HAS_H0) {
            #pragma unroll
            for (int s = 0; s < 4; ++s) {
                accR  = __builtin_amdgcn_mfma_f32_16x16x32_bf16(bwh[0][s], ah[s], accR, 0, 0, 0);
                accZ  = __builtin_amdgcn_mfma_f32_16x16x32_bf16(bwh[1][s], ah[s], accZ, 0, 0, 0);
                accNh = __builtin_amdgcn_mfma_f32_16x16x32_bf16(bwh[2][s], ah[s], accNh, 0, 0, 0);
            }
        }

        float h0v[4] = {0.f, 0.f, 0.f, 0.f};
        if (HAS_H0) {
            short4 h04 = *(const short4*)&hs[row * 136 + g0];
            h0v[0] = b2f((ushort_t)h04.x); h0v[1] = b2f((ushort_t)h04.y);
            h0v[2] = b2f((ushort_t)h04.z); h0v[3] = b2f((ushort_t)h04.w);
        }
        ushort_t ov[4];
        #pragma unroll
        for (int r = 0; r < 4; ++r) {
            float rr = sigf(accR[r] + bR[r]);
            float zz = sigf(accZ[r] + bZ[r]);
            float hn = HAS_H0 ? (accNh[r] + bhN[r]) : bhN[r];
            float nn = tanh_f(accN[r] + biN[r] + rr * hn);
            float h = nn + zz * (h0v[r] - nn);
            ov[r] = f2b(h);
        }
        *(short4*)(hbuf + (size_t)(base + row) * 128 + g0) = *(const short4*)ov;
    }
}

// ---------------------------------------------------------------------------
// Attention + sibling-max. Round-4 attn structure (512 thr, 32 parents =
// 128 child rows) + free max epilogue (children already staged in LDS).
// Writes h0 (parent-row indexed) and bf16 pmax (same indexing).
// ---------------------------------------------------------------------------
__global__ __launch_bounds__(512, 2) void attnmax_mfma(
    const ushort_t* __restrict__ hch, ushort_t* __restrict__ h0out,
    ushort_t* __restrict__ pmaxs,
    const ushort_t* __restrict__ swt, const float* __restrict__ sb,
    const float* __restrict__ cw)
{
    __shared__ ushort_t chs[128 * 136];
    __shared__ float scp[8][128];
    __shared__ float sc[128];
    __shared__ float al[4][32];

    const int t = threadIdx.x;
    const int pbase = blockIdx.x * 32;
    const int pnode = pbase >> 8;
    const int b0 = pbase & 255;

    {
        int lr = t >> 2, c0 = (t & 3) * 32;
        int k = lr >> 5, bl = lr & 31;
        const ushort_t* src = hch + ((size_t)(4 * pnode + k) * 256 + b0 + bl) * 128 + c0;
        ushort_t* dst = &chs[lr * 136 + c0];
        #pragma unroll
        for (int i = 0; i < 4; ++i) *(s8*)(dst + 8 * i) = *(const s8*)(src + 8 * i);
    }

    const int lane = t & 63, w = t >> 6;
    const int quad = lane >> 4, l15 = lane & 15;
    const int fA = w * 16 + l15;
    const int f0 = w * 16 + quad * 4;

    s8 bsw[4];
    {
        const ushort_t* wp = swt + (size_t)fA * 128 + quad * 8;
        #pragma unroll
        for (int s = 0; s < 4; ++s) bsw[s] = *(const s8*)(wp + 32 * s);
    }
    float sb4[4], cw4[4];
    {
        float4 a = *(const float4*)(sb + f0);
        float4 b = *(const float4*)(cw + f0);
        sb4[0] = a.x; sb4[1] = a.y; sb4[2] = a.z; sb4[3] = a.w;
        cw4[0] = b.x; cw4[1] = b.y; cw4[2] = b.z; cw4[3] = b.w;
    }
    __syncthreads();

    #pragma unroll 1
    for (int mt = 0; mt < 8; ++mt) {
        const int crow = mt * 16 + l15;
        s8 a[4];
        const ushort_t* ap = &chs[crow * 136 + quad * 8];
        #pragma unroll
        for (int s = 0; s < 4; ++s) a[s] = *(const s8*)(ap + 32 * s);

        f4 acc = (f4)0.f;
        #pragma unroll
        for (int s = 0; s < 4; ++s)
            acc = __builtin_amdgcn_mfma_f32_16x16x32_bf16(bsw[s], a[s], acc, 0, 0, 0);

        float part = 0.f;
        #pragma unroll
        for (int r = 0; r < 4; ++r)
            part += tanh_f(acc[r] + sb4[r]) * cw4[r];
        part += __shfl_xor(part, 16);
        part += __shfl_xor(part, 32);
        if (quad == 0) scp[w][crow] = part;
    }
    __syncthreads();

    if (t < 128) {
        float s = 0.f;
        #pragma unroll
        for (int ww = 0; ww < 8; ++ww) s += scp[ww][t];
        sc[t] = tanh_f(s);
    }
    __syncthreads();

    if (t < 32) {
        float s0 = sc[t], s1 = sc[32 + t], s2 = sc[64 + t], s3 = sc[96 + t];
        float m = fmaxf(fmaxf(s0, s1), fmaxf(s2, s3));
        float e0 = fexp2f((s0 - m) * 1.44269504f), e1 = fexp2f((s1 - m) * 1.44269504f);
        float e2 = fexp2f((s2 - m) * 1.44269504f), e3 = fexp2f((s3 - m) * 1.44269504f);
        float inv = frcpf(e0 + e1 + e2 + e3);
        al[0][t] = e0 * inv; al[1][t] = e1 * inv; al[2][t] = e2 * inv; al[3][t] = e3 * inv;
    }
    __syncthreads();

    {
        int bl = t >> 4, e0 = (t & 15) * 8;
        float a0 = al[0][bl], a1 = al[1][bl], a2 = al[2][bl], a3 = al[3][bl];
        s8 c0v = *(const s8*)&chs[(0 * 32 + bl) * 136 + e0];
        s8 c1v = *(const s8*)&chs[(1 * 32 + bl) * 136 + e0];
        s8 c2v = *(const s8*)&chs[(2 * 32 + bl) * 136 + e0];
        s8 c3v = *(const s8*)&chs[(3 * 32 + bl) * 136 + e0];
        ushort_t ov[8], mv[8];
        #pragma unroll
        for (int j = 0; j < 8; ++j) {
            float x0 = b2f((ushort_t)c0v[j]), x1 = b2f((ushort_t)c1v[j]);
            float x2 = b2f((ushort_t)c2v[j]), x3 = b2f((ushort_t)c3v[j]);
            ov[j] = f2b(a0 * x0 + a1 * x1 + a2 * x2 + a3 * x3);
            mv[j] = f2b(fmaxf(fmaxf(x0, x1), fmaxf(x2, x3)));   // exact on bf16
        }
        size_t ro = (size_t)(pbase + bl) * 128 + e0;
        *(s8*)(h0out + ro) = *(const s8*)ov;
        *(s8*)(pmaxs + ro) = *(const s8*)mv;
    }
}

// ---------------------------------------------------------------------------
// Device grid barrier (single-use counters, zeroed by cvt_kernel).
// All 256 blocks co-resident: 38 KB LDS / 8 waves per block -> even 2-per-CU
// packing keeps every block resident; no deadlock.
// ---------------------------------------------------------------------------
__device__ __forceinline__ void grid_barrier(unsigned* cnt, unsigned nblk) {
    __syncthreads();
    if (threadIdx.x == 0) {
        __threadfence();
        __hip_atomic_fetch_add(cnt, 1u, __ATOMIC_RELEASE, __HIP_MEMORY_SCOPE_AGENT);
        while (__hip_atomic_load(cnt, __ATOMIC_ACQUIRE, __HIP_MEMORY_SCOPE_AGENT) < nblk)
            __builtin_amdgcn_s_sleep(1);
        __threadfence();
    }
    __syncthreads();
}

// ---------------------------------------------------------------------------
// Fused level step for the tiny tail levels (round-6 level_kernel body,
// verified correct). MODE 1: GRU+attn+max; MODE 2: root GRU -> pmax slot.
// Block = 64 child rows = 4 siblings x 16 batch; p = sibling-group, y = batch tile.
// ---------------------------------------------------------------------------
template <int MODE>
__device__ void fused_level(
    int p, int y,
    const int* __restrict__ tokens, const ushort_t* __restrict__ embb,
    const ushort_t* __restrict__ wihb, const ushort_t* __restrict__ whhb,
    const float* __restrict__ bih, const float* __restrict__ bhh,
    const ushort_t* __restrict__ swtb, const float* __restrict__ sbv,
    const float* __restrict__ cwv,
    const ushort_t* __restrict__ h0in, ushort_t* __restrict__ h0out,
    ushort_t* __restrict__ pmaxs, int tok_start,
    ushort_t* xs, ushort_t* hs, float (*scp)[64], float* sc, float (*al)[16])
{
    constexpr bool ATTN = (MODE != 2);
    const int t = threadIdx.x;

    {
        int lr = t >> 3, ci = (t & 7) * 16;
        int node, b;
        if (ATTN) { node = 4 * p + (lr >> 4); b = y * 16 + (lr & 15); }
        else      { node = 0;                 b = y * 64 + lr; }
        int tok = tokens[(tok_start + node) * 256 + b];
        const ushort_t* src = embb + (size_t)tok * 128 + ci;
        ushort_t* dst = &xs[lr * 136 + ci];
        *(s8*)dst       = *(const s8*)src;
        *(s8*)(dst + 8) = *(const s8*)(src + 8);
        const ushort_t* hsrc = h0in + ((size_t)node * 256 + b) * 128 + ci;
        ushort_t* hdst = &hs[lr * 136 + ci];
        *(s8*)hdst       = *(const s8*)hsrc;
        *(s8*)(hdst + 8) = *(const s8*)(hsrc + 8);
    }

    const int lane = t & 63, w = t >> 6;
    const int quad = lane >> 4, l15 = lane & 15;
    const int gA = w * 16 + l15;
    const int g0 = w * 16 + quad * 4;

    s8 bwi[3][4], bwh[3][4];
    #pragma unroll
    for (int gm = 0; gm < 3; ++gm) {
        const ushort_t* wp = wihb + (size_t)(gm * 128 + gA) * 128 + quad * 8;
        #pragma unroll
        for (int s = 0; s < 4; ++s) bwi[gm][s] = *(const s8*)(wp + 32 * s);
        const ushort_t* wp2 = whhb + (size_t)(gm * 128 + gA) * 128 + quad * 8;
        #pragma unroll
        for (int s = 0; s < 4; ++s) bwh[gm][s] = *(const s8*)(wp2 + 32 * s);
    }

    f4 cR0, cZ0, cN0, cNh0;
    {
        float4 a = *(const float4*)(bih + g0);
        float4 b = *(const float4*)(bhh + g0);
        cR0[0] = a.x + b.x; cR0[1] = a.y + b.y; cR0[2] = a.z + b.z; cR0[3] = a.w + b.w;
        float4 c = *(const float4*)(bih + 128 + g0);
        float4 d = *(const float4*)(bhh + 128 + g0);
        cZ0[0] = c.x + d.x; cZ0[1] = c.y + d.y; cZ0[2] = c.z + d.z; cZ0[3] = c.w + d.w;
        float4 e = *(const float4*)(bih + 256 + g0);
        float4 f = *(const float4*)(bhh + 256 + g0);
        cN0[0] = e.x; cN0[1] = e.y; cN0[2] = e.z; cN0[3] = e.w;
        cNh0[0] = f.x; cNh0[1] = f.y; cNh0[2] = f.z; cNh0[3] = f.w;
    }

    __syncthreads();

    #pragma unroll 1
    for (int mt = 0; mt < 4; ++mt) {
        const int row = mt * 16 + l15;
        s8 ax[4], ah[4];
        {
            const ushort_t* ap = &xs[row * 136 + quad * 8];
            #pragma unroll
            for (int s = 0; s < 4; ++s) ax[s] = *(const s8*)(ap + 32 * s);
            const ushort_t* hp = &hs[row * 136 + quad * 8];
            #pragma unroll
            for (int s = 0; s < 4; ++s) ah[s] = *(const s8*)(hp + 32 * s);
        }

        f4 accR = cR0, accZ = cZ0, accN = cN0, accNh = cNh0;
        #pragma unroll
        for (int s = 0; s < 4; ++s) {
            accR = __builtin_amdgcn_mfma_f32_16x16x32_bf16(bwi[0][s], ax[s], accR, 0, 0, 0);
            accZ = __builtin_amdgcn_mfma_f32_16x16x32_bf16(bwi[1][s], ax[s], accZ, 0, 0, 0);
            accN = __builtin_amdgcn_mfma_f32_16x16x32_bf16(bwi[2][s], ax[s], accN, 0, 0, 0);
        }
        #pragma unroll
        for (int s = 0; s < 4; ++s) {
            accR  = __builtin_amdgcn_mfma_f32_16x16x32_bf16(bwh[0][s], ah[s], accR, 0, 0, 0);
            accZ  = __builtin_amdgcn_mfma_f32_16x16x32_bf16(bwh[1][s], ah[s], accZ, 0, 0, 0);
            accNh = __builtin_amdgcn_mfma_f32_16x16x32_bf16(bwh[2][s], ah[s], accNh, 0, 0, 0);
        }

        __syncthreads();   // tile mt reads done -> safe to overwrite xs

        float h0v[4];
        {
            short4 h04 = *(const short4*)&hs[row * 136 + g0];
            h0v[0] = b2f((ushort_t)h04.x); h0v[1] = b2f((ushort_t)h04.y);
            h0v[2] = b2f((ushort_t)h04.z); h0v[3] = b2f((ushort_t)h04.w);
        }
        ushort_t ov[4];
        #pragma unroll
        for (int r = 0; r < 4; ++r) {
            float rr = sigf(accR[r]);
            float zz = sigf(accZ[r]);
            float nn = tanh_f(accN[r] + rr * accNh[r]);
            float h = nn + zz * (h0v[r] - nn);
            ov[r] = f2b(h);
        }
        *(short4*)&xs[row * 136 + g0] = *(const short4*)ov;
    }
    __syncthreads();

    if (MODE == 2) {
        int row = t >> 3, ci = (t & 7) * 16;
        ushort_t* d = pmaxs + ((size_t)(y * 64 + row)) * 128 + ci;
        const ushort_t* s_ = &xs[row * 136 + ci];
        *(s8*)d       = *(const s8*)s_;
        *(s8*)(d + 8) = *(const s8*)(s_ + 8);
        return;
    }

    // attention over the 4 siblings
    s8 bsw[4];
    {
        const ushort_t* wp = swtb + (size_t)gA * 128 + quad * 8;
        #pragma unroll
        for (int s = 0; s < 4; ++s) bsw[s] = *(const s8*)(wp + 32 * s);
    }
    f4 sb0;
    float cw4[4];
    {
        float4 a = *(const float4*)(sbv + g0);
        sb0[0] = a.x; sb0[1] = a.y; sb0[2] = a.z; sb0[3] = a.w;
        float4 b = *(const float4*)(cwv + g0);
        cw4[0] = b.x; cw4[1] = b.y; cw4[2] = b.z; cw4[3] = b.w;
    }

    #pragma unroll 1
    for (int mt = 0; mt < 4; ++mt) {
        const int crow = mt * 16 + l15;
        s8 a[4];
        const ushort_t* ap = &xs[crow * 136 + quad * 8];
        #pragma unroll
        for (int s = 0; s < 4; ++s) a[s] = *(const s8*)(ap + 32 * s);

        f4 acc = sb0;
        #pragma unroll
        for (int s = 0; s < 4; ++s)
            acc = __builtin_amdgcn_mfma_f32_16x16x32_bf16(bsw[s], a[s], acc, 0, 0, 0);

        float part = 0.f;
        #pragma unroll
        for (int r = 0; r < 4; ++r)
            part += tanh_f(acc[r]) * cw4[r];
        part += __shfl_xor(part, 16);
        part += __shfl_xor(part, 32);
        if (quad == 0) scp[w][crow] = part;
    }
    __syncthreads();

    if (t < 64) {
        float s_ = 0.f;
        #pragma unroll
        for (int ww = 0; ww < 8; ++ww) s_ += scp[ww][t];
        sc[t] = tanh_f(s_);
    }
    __syncthreads();

    if (t < 16) {
        float s0 = sc[t], s1 = sc[16 + t], s2 = sc[32 + t], s3 = sc[48 + t];
        float m = fmaxf(fmaxf(s0, s1), fmaxf(s2, s3));
        float e0 = fexp2f((s0 - m) * 1.44269504f), e1 = fexp2f((s1 - m) * 1.44269504f);
        float e2 = fexp2f((s2 - m) * 1.44269504f), e3 = fexp2f((s3 - m) * 1.44269504f);
        float inv = frcpf(e0 + e1 + e2 + e3);
        al[0][t] = e0 * inv; al[1][t] = e1 * inv; al[2][t] = e2 * inv; al[3][t] = e3 * inv;
    }
    __syncthreads();

    if (t < 256) {
        int bl = t >> 4, e0 = (t & 15) * 8;
        float a0 = al[0][bl], a1 = al[1][bl], a2 = al[2][bl], a3 = al[3][bl];
        s8 c0 = *(const s8*)&xs[(0 * 16 + bl) * 136 + e0];
        s8 c1 = *(const s8*)&xs[(1 * 16 + bl) * 136 + e0];
        s8 c2 = *(const s8*)&xs[(2 * 16 + bl) * 136 + e0];
        s8 c3 = *(const s8*)&xs[(3 * 16 + bl) * 136 + e0];
        ushort_t ov[8];
        #pragma unroll
        for (int j = 0; j < 8; ++j) {
            float v = a0 * b2f((ushort_t)c0[j]) + a1 * b2f((ushort_t)c1[j])
                    + a2 * b2f((ushort_t)c2[j]) + a3 * b2f((ushort_t)c3[j]);
            ov[j] = f2b(v);
        }
        *(s8*)(h0out + ((size_t)p * 256 + y * 16 + bl) * 128 + e0) = *(const s8*)ov;
    } else {
        int tt = t - 256;
        int bl = tt >> 4, e0 = (tt & 15) * 8;
        s8 c0 = *(const s8*)&xs[(0 * 16 + bl) * 136 + e0];
        s8 c1 = *(const s8*)&xs[(1 * 16 + bl) * 136 + e0];
        s8 c2 = *(const s8*)&xs[(2 * 16 + bl) * 136 + e0];
        s8 c3 = *(const s8*)&xs[(3 * 16 + bl) * 136 + e0];
        ushort_t ov[8];
        #pragma unroll
        for (int j = 0; j < 8; ++j) {
            float v = fmaxf(fmaxf(b2f((ushort_t)c0[j]), b2f((ushort_t)c1[j])),
                            fmaxf(b2f((ushort_t)c2[j]), b2f((ushort_t)c3[j])));
            ov[j] = f2b(v);
        }
        *(s8*)(pmaxs + (size_t)p * 32768 + (size_t)(y * 16 + bl) * 128 + e0) = *(const s8*)ov;
    }
}

// ---------------------------------------------------------------------------
// Tail kernel: levels 3,2,1 + root in ONE launch with in-kernel grid barriers.
// Grid = 256 blocks (all co-resident). Tiny levels are latency-bound, so
// in-kernel steps (~few µs) beat per-level kernel launches.
// ---------------------------------------------------------------------------
__global__ __launch_bounds__(512, 2) void tail_kernel(
    const int* __restrict__ tokens, const ushort_t* __restrict__ embb,
    const ushort_t* __restrict__ wihb, const ushort_t* __restrict__ whhb,
    const float* __restrict__ bih, const float* __restrict__ bhh,
    const ushort_t* __restrict__ swtb, const float* __restrict__ sbv,
    const float* __restrict__ cwv,
    const ushort_t* __restrict__ h0_3, ushort_t* __restrict__ h0_2,
    ushort_t* __restrict__ h0_1, ushort_t* __restrict__ h0_0,
    ushort_t* __restrict__ pmax, unsigned* __restrict__ bar)
{
    __shared__ ushort_t xs[64 * 136];
    __shared__ ushort_t hs[64 * 136];
    __shared__ float scp[8][64];
    __shared__ float sc[64];
    __shared__ float al[4][16];

    const unsigned blk = blockIdx.x;

    // level 3: 64 nodes -> h3 (LDS) -> h0_2 (16 nodes) + pmax[320..335]
    fused_level<1>((int)(blk >> 4), (int)(blk & 15),
        tokens, embb, wihb, whhb, bih, bhh, swtb, sbv, cwv,
        h0_3, h0_2, pmax + (size_t)320 * 32768, 21,
        xs, hs, scp, sc, al);
    grid_barrier(bar + 0, 256);

    // level 2: 16 nodes -> h0_1 (4 nodes) + pmax[336..339]
    if (blk < 64)
        fused_level<1>((int)(blk >> 4), (int)(blk & 15),
            tokens, embb, wihb, whhb, bih, bhh, swtb, sbv, cwv,
            h0_2, h0_1, pmax + (size_t)336 * 32768, 5,
            xs, hs, scp, sc, al);
    grid_barrier(bar + 1, 256);

    // level 1: 4 nodes -> h0_0 (1 node) + pmax[340]
    if (blk < 16)
        fused_level<1>(0, (int)blk,
            tokens, embb, wihb, whhb, bih, bhh, swtb, sbv, cwv,
            h0_1, h0_0, pmax + (size_t)340 * 32768, 1,
            xs, hs, scp, sc, al);
    grid_barrier(bar + 2, 256);

    // root: GRU only -> pmax[341]
    if (blk < 4)
        fused_level<2>(0, (int)blk,
            tokens, embb, wihb, whhb, bih, bhh, swtb, sbv, cwv,
            h0_0, nullptr, pmax + (size_t)341 * 32768, 0,
            xs, hs, scp, sc, al);
}

// ---------------------------------------------------------------------------
// Final: out[e] = max over 342 bf16 pmax slots. 128 blocks x 256 thr, 1 e each.
// ---------------------------------------------------------------------------
#define N_SLOTS 342
__global__ __launch_bounds__(256) void final_max(
    const ushort_t* __restrict__ pmax, float* __restrict__ out)
{
    int e = blockIdx.x * 256 + threadIdx.x;   // 0..32767
    float v = b2f(pmax[e]);
    #pragma unroll 2
    for (int s = 1; s < N_SLOTS; ++s)
        v = fmaxf(v, b2f(pmax[(size_t)s * 32768 + e]));
    out[e] = v;
}

extern "C" void kernel_launch(void* const* d_in, const int* in_sizes, int n_in,
                              void* d_out, int out_size, void* d_ws, size_t ws_size,
                              hipStream_t stream)
{
    const int*   tokens = (const int*)d_in[0];
    const float* emb    = (const float*)d_in[1];
    const float* Wih    = (const float*)d_in[2];
    const float* Whh    = (const float*)d_in[3];
    const float* bih    = (const float*)d_in[4];
    const float* bhh    = (const float*)d_in[5];
    const float* SW     = (const float*)d_in[6];
    const float* sb     = (const float*)d_in[7];
    const float* cw     = (const float*)d_in[8];
    float* out = (float*)d_out;

    // ws layout (shorts unless noted)
    ushort_t* embb = (ushort_t*)d_ws;                        // 12.8 MB
    ushort_t* wihb = embb + (size_t)EMB_N;
    ushort_t* whhb = wihb + W_N;
    ushort_t* swtb = whhb + W_N;
    ushort_t* h5   = swtb + SW_N;                            // 1024n: 67.1 MB
    ushort_t* h4   = h5 + (size_t)1024 * 32768;              // 256n: 16.8 MB
    ushort_t* h0_4 = h4 + (size_t)256 * 32768;               // 256n
    ushort_t* h0_3 = h0_4 + (size_t)256 * 32768;             // 64n
    ushort_t* h0_2 = h0_3 + (size_t)64 * 32768;              // 16n
    ushort_t* h0_1 = h0_2 + (size_t)16 * 32768;              // 4n
    ushort_t* h0_0 = h0_1 + (size_t)4 * 32768;               // 1n
    ushort_t* pmax = h0_0 + (size_t)1 * 32768;               // 342 slots: 22.4 MB
    unsigned* bar  = (unsigned*)(pmax + (size_t)N_SLOTS * 32768);

    // pmax slots: L5-max: 0..255 | L4: 256..319 | L3: 320..335 | L2: 336..339
    //             L1: 340 | root-h: 341

    cvt_kernel<<<(CVT_N / 4 + 255) / 256, 256, 0, stream>>>(
        emb, Wih, Whh, SW, embb, wihb, whhb, swtb, bar);

    // L5 leaf GRU (1024 nodes): 262144 rows
    gru_mfma<false><<<2048, 512, 0, stream>>>(
        tokens, embb, wihb, whhb, bih, bhh, nullptr, h5, 341);
    // attn+max over h5 -> h0_4 + pmax[0..255] (65536 parent rows)
    attnmax_mfma<<<2048, 512, 0, stream>>>(h5, h0_4, pmax, swtb, sb, cw);

    // L4 GRU (256 nodes): 65536 rows
    gru_mfma<true><<<512, 512, 0, stream>>>(
        tokens, embb, wihb, whhb, bih, bhh, h0_4, h4, 85);
    // attn+max over h4 -> h0_3 + pmax[256..319] (16384 parent rows)
    attnmax_mfma<<<512, 512, 0, stream>>>(h4, h0_3, pmax + (size_t)256 * 32768,
                                          swtb, sb, cw);

    // levels 3..0 in one kernel
    tail_kernel<<<256, 512, 0, stream>>>(
        tokens, embb, wihb, whhb, bih, bhh, swtb, sb, cw,
        h0_3, h0_2, h0_1, h0_0, pmax, bar);

    final_max<<<128, 256, 0, stream>>>(pmax, out);
}

// Round 8
// 255.855 us; speedup vs baseline: 1.6462x; 1.6462x over previous
//
#include <hip/hip_runtime.h>
#include <math.h>

typedef short s8 __attribute__((ext_vector_type(8)));   // 8 bf16 in 4 VGPRs
typedef float f4 __attribute__((ext_vector_type(4)));   // MFMA 16x16 acc
typedef unsigned short ushort_t;

__device__ __forceinline__ float fexp2f(float x) { return __builtin_amdgcn_exp2f(x); }
__device__ __forceinline__ float frcpf(float x)  { return __builtin_amdgcn_rcpf(x); }
__device__ __forceinline__ float sigf(float x) {
    return frcpf(1.f + fexp2f(x * -1.44269504f));
}
__device__ __forceinline__ float tanh_f(float x) {
    float e = fexp2f(x * 2.88539008f);
    return 1.f - 2.f * frcpf(e + 1.f);
}
__device__ __forceinline__ ushort_t f2b(float f) {
    unsigned u = __float_as_uint(f);
    u = (u + 0x7FFF + ((u >> 16) & 1)) >> 16;   // RNE
    return (ushort_t)u;
}
__device__ __forceinline__ float b2f(ushort_t b) {
    return __uint_as_float(((unsigned)b) << 16);
}

// ---------------------------------------------------------------------------
// Convert emb / Wih / Whh / SW^T to bf16, 4 elems/thread.
// ---------------------------------------------------------------------------
#define EMB_N   6400000          // 50000*128
#define W_N     49152            // 384*128
#define SW_N    16384            // 128*128
#define CVT_N   (EMB_N + 2 * W_N + SW_N)

__global__ __launch_bounds__(256) void cvt_kernel(
    const float* __restrict__ emb, const float* __restrict__ wih,
    const float* __restrict__ whh, const float* __restrict__ sw,
    ushort_t* __restrict__ embb, ushort_t* __restrict__ wihb,
    ushort_t* __restrict__ whhb, ushort_t* __restrict__ swtb)
{
    int i = (blockIdx.x * 256 + threadIdx.x) * 4;
    if (i >= CVT_N) return;
    if (i < EMB_N) {
        float4 v = *(const float4*)(emb + i);
        short4 o; o.x = f2b(v.x); o.y = f2b(v.y); o.z = f2b(v.z); o.w = f2b(v.w);
        *(short4*)(embb + i) = o;
    } else if (i < EMB_N + W_N) {
        int j = i - EMB_N;
        float4 v = *(const float4*)(wih + j);
        short4 o; o.x = f2b(v.x); o.y = f2b(v.y); o.z = f2b(v.z); o.w = f2b(v.w);
        *(short4*)(wihb + j) = o;
    } else if (i < EMB_N + 2 * W_N) {
        int j = i - EMB_N - W_N;
        float4 v = *(const float4*)(whh + j);
        short4 o; o.x = f2b(v.x); o.y = f2b(v.y); o.z = f2b(v.z); o.w = f2b(v.w);
        *(short4*)(whhb + j) = o;
    } else {
        int j = i - EMB_N - 2 * W_N;
        int f = j >> 7, e0 = j & 127;
        short4 o;
        o.x = f2b(sw[(e0 + 0) * 128 + f]);
        o.y = f2b(sw[(e0 + 1) * 128 + f]);
        o.z = f2b(sw[(e0 + 2) * 128 + f]);
        o.w = f2b(sw[(e0 + 3) * 128 + f]);
        *(short4*)(swtb + j) = o;        // SWt[f][e]
    }
}

// ---------------------------------------------------------------------------
// GRU step (round-4 structure: best measured throughput). Block = 512 thr,
// 128 rows (8 M-tiles); wave w owns gate cols w*16..+15; operand-swapped MFMA.
// ---------------------------------------------------------------------------
template <bool HAS_H0>
__global__ __launch_bounds__(512, 2) void gru_mfma(
    const int* __restrict__ tokens, const ushort_t* __restrict__ embb,
    const ushort_t* __restrict__ wihb, const ushort_t* __restrict__ whhb,
    const float* __restrict__ bih, const float* __restrict__ bhh,
    const ushort_t* __restrict__ h0buf, ushort_t* __restrict__ hbuf,
    int lvl_start)
{
    __shared__ ushort_t xs[128 * 136];
    __shared__ ushort_t hs[HAS_H0 ? 128 * 136 : 8];

    const int t = threadIdx.x;
    const int base = blockIdx.x * 128;

    {
        int rl = t >> 2, c0 = (t & 3) * 32;
        int row = base + rl;
        int tok = tokens[(lvl_start + (row >> 8)) * 256 + (row & 255)];
        const ushort_t* src = embb + (size_t)tok * 128 + c0;
        ushort_t* dst = &xs[rl * 136 + c0];
        #pragma unroll
        for (int i = 0; i < 4; ++i) *(s8*)(dst + 8 * i) = *(const s8*)(src + 8 * i);
        if (HAS_H0) {
            const ushort_t* hsrc = h0buf + (size_t)row * 128 + c0;
            ushort_t* hdst = &hs[rl * 136 + c0];
            #pragma unroll
            for (int i = 0; i < 4; ++i) *(s8*)(hdst + 8 * i) = *(const s8*)(hsrc + 8 * i);
        }
    }

    const int lane = t & 63, w = t >> 6;
    const int quad = lane >> 4, l15 = lane & 15;
    const int gA = w * 16 + l15;
    const int g0 = w * 16 + quad * 4;

    s8 bwi[3][4], bwh[3][4];
    #pragma unroll
    for (int gm = 0; gm < 3; ++gm) {
        const ushort_t* wp = wihb + (size_t)(gm * 128 + gA) * 128 + quad * 8;
        #pragma unroll
        for (int s = 0; s < 4; ++s) bwi[gm][s] = *(const s8*)(wp + 32 * s);
    }
    if (HAS_H0) {
        #pragma unroll
        for (int gm = 0; gm < 3; ++gm) {
            const ushort_t* wp = whhb + (size_t)(gm * 128 + gA) * 128 + quad * 8;
            #pragma unroll
            for (int s = 0; s < 4; ++s) bwh[gm][s] = *(const s8*)(wp + 32 * s);
        }
    }

    float bR[4], bZ[4], biN[4], bhN[4];
    {
        float4 a = *(const float4*)(bih + g0);
        float4 b = *(const float4*)(bhh + g0);
        bR[0] = a.x + b.x; bR[1] = a.y + b.y; bR[2] = a.z + b.z; bR[3] = a.w + b.w;
        float4 c = *(const float4*)(bih + 128 + g0);
        float4 d = *(const float4*)(bhh + 128 + g0);
        bZ[0] = c.x + d.x; bZ[1] = c.y + d.y; bZ[2] = c.z + d.z; bZ[3] = c.w + d.w;
        float4 e = *(const float4*)(bih + 256 + g0);
        float4 f = *(const float4*)(bhh + 256 + g0);
        biN[0] = e.x; biN[1] = e.y; biN[2] = e.z; biN[3] = e.w;
        bhN[0] = f.x; bhN[1] = f.y; bhN[2] = f.z; bhN[3] = f.w;
    }

    __syncthreads();

    #pragma unroll 1
    for (int mt = 0; mt < 8; ++mt) {
        const int row = mt * 16 + l15;
        s8 ax[4], ah[4];
        {
            const ushort_t* ap = &xs[row * 136 + quad * 8];
            #pragma unroll
            for (int s = 0; s < 4; ++s) ax[s] = *(const s8*)(ap + 32 * s);
            if (HAS_H0) {
                const ushort_t* hp = &hs[row * 136 + quad * 8];
                #pragma unroll
                for (int s = 0; s < 4; ++s) ah[s] = *(const s8*)(hp + 32 * s);
            }
        }

        f4 accR = (f4)0.f, accZ = (f4)0.f, accN = (f4)0.f, accNh = (f4)0.f;
        #pragma unroll
        for (int s = 0; s < 4; ++s) {
            accR = __builtin_amdgcn_mfma_f32_16x16x32_bf16(bwi[0][s], ax[s], accR, 0, 0, 0);
            accZ = __builtin_amdgcn_mfma_f32_16x16x32_bf16(bwi[1][s], ax[s], accZ, 0, 0, 0);
            accN = __builtin_amdgcn_mfma_f32_16x16x32_bf16(bwi[2][s], ax[s], accN, 0, 0, 0);
        }
        if (HAS_H0) {
            #pragma unroll
            for (int s = 0; s < 4; ++s) {
                accR  = __builtin_amdgcn_mfma_f32_16x16x32_bf16(bwh[0][s], ah[s], accR, 0, 0, 0);
                accZ  = __builtin_amdgcn_mfma_f32_16x16x32_bf16(bwh[1][s], ah[s], accZ, 0, 0, 0);
                accNh = __builtin_amdgcn_mfma_f32_16x16x32_bf16(bwh[2][s], ah[s], accNh, 0, 0, 0);
            }
        }

        float h0v[4] = {0.f, 0.f, 0.f, 0.f};
        if (HAS_H0) {
            short4 h04 = *(const short4*)&hs[row * 136 + g0];
            h0v[0] = b2f((ushort_t)h04.x); h0v[1] = b2f((ushort_t)h04.y);
            h0v[2] = b2f((ushort_t)h04.z); h0v[3] = b2f((ushort_t)h04.w);
        }
        ushort_t ov[4];
        #pragma unroll
        for (int r = 0; r < 4; ++r) {
            float rr = sigf(accR[r] + bR[r]);
            float zz = sigf(accZ[r] + bZ[r]);
            float hn = HAS_H0 ? (accNh[r] + bhN[r]) : bhN[r];
            float nn = tanh_f(accN[r] + biN[r] + rr * hn);
            float h = nn + zz * (h0v[r] - nn);
            ov[r] = f2b(h);
        }
        *(short4*)(hbuf + (size_t)(base + row) * 128 + g0) = *(const short4*)ov;
    }
}

// ---------------------------------------------------------------------------
// Attention + sibling-max. 512 thr, 32 parents = 128 child rows; free max
// epilogue (children already staged in LDS). Writes h0 and bf16 pmax.
// ---------------------------------------------------------------------------
__global__ __launch_bounds__(512, 2) void attnmax_mfma(
    const ushort_t* __restrict__ hch, ushort_t* __restrict__ h0out,
    ushort_t* __restrict__ pmaxs,
    const ushort_t* __restrict__ swt, const float* __restrict__ sb,
    const float* __restrict__ cw)
{
    __shared__ ushort_t chs[128 * 136];
    __shared__ float scp[8][128];
    __shared__ float sc[128];
    __shared__ float al[4][32];

    const int t = threadIdx.x;
    const int pbase = blockIdx.x * 32;
    const int pnode = pbase >> 8;
    const int b0 = pbase & 255;

    {
        int lr = t >> 2, c0 = (t & 3) * 32;
        int k = lr >> 5, bl = lr & 31;
        const ushort_t* src = hch + ((size_t)(4 * pnode + k) * 256 + b0 + bl) * 128 + c0;
        ushort_t* dst = &chs[lr * 136 + c0];
        #pragma unroll
        for (int i = 0; i < 4; ++i) *(s8*)(dst + 8 * i) = *(const s8*)(src + 8 * i);
    }

    const int lane = t & 63, w = t >> 6;
    const int quad = lane >> 4, l15 = lane & 15;
    const int fA = w * 16 + l15;
    const int f0 = w * 16 + quad * 4;

    s8 bsw[4];
    {
        const ushort_t* wp = swt + (size_t)fA * 128 + quad * 8;
        #pragma unroll
        for (int s = 0; s < 4; ++s) bsw[s] = *(const s8*)(wp + 32 * s);
    }
    float sb4[4], cw4[4];
    {
        float4 a = *(const float4*)(sb + f0);
        float4 b = *(const float4*)(cw + f0);
        sb4[0] = a.x; sb4[1] = a.y; sb4[2] = a.z; sb4[3] = a.w;
        cw4[0] = b.x; cw4[1] = b.y; cw4[2] = b.z; cw4[3] = b.w;
    }
    __syncthreads();

    #pragma unroll 1
    for (int mt = 0; mt < 8; ++mt) {
        const int crow = mt * 16 + l15;
        s8 a[4];
        const ushort_t* ap = &chs[crow * 136 + quad * 8];
        #pragma unroll
        for (int s = 0; s < 4; ++s) a[s] = *(const s8*)(ap + 32 * s);

        f4 acc = (f4)0.f;
        #pragma unroll
        for (int s = 0; s < 4; ++s)
            acc = __builtin_amdgcn_mfma_f32_16x16x32_bf16(bsw[s], a[s], acc, 0, 0, 0);

        float part = 0.f;
        #pragma unroll
        for (int r = 0; r < 4; ++r)
            part += tanh_f(acc[r] + sb4[r]) * cw4[r];
        part += __shfl_xor(part, 16);
        part += __shfl_xor(part, 32);
        if (quad == 0) scp[w][crow] = part;
    }
    __syncthreads();

    if (t < 128) {
        float s = 0.f;
        #pragma unroll
        for (int ww = 0; ww < 8; ++ww) s += scp[ww][t];
        sc[t] = tanh_f(s);
    }
    __syncthreads();

    if (t < 32) {
        float s0 = sc[t], s1 = sc[32 + t], s2 = sc[64 + t], s3 = sc[96 + t];
        float m = fmaxf(fmaxf(s0, s1), fmaxf(s2, s3));
        float e0 = fexp2f((s0 - m) * 1.44269504f), e1 = fexp2f((s1 - m) * 1.44269504f);
        float e2 = fexp2f((s2 - m) * 1.44269504f), e3 = fexp2f((s3 - m) * 1.44269504f);
        float inv = frcpf(e0 + e1 + e2 + e3);
        al[0][t] = e0 * inv; al[1][t] = e1 * inv; al[2][t] = e2 * inv; al[3][t] = e3 * inv;
    }
    __syncthreads();

    {
        int bl = t >> 4, e0 = (t & 15) * 8;
        float a0 = al[0][bl], a1 = al[1][bl], a2 = al[2][bl], a3 = al[3][bl];
        s8 c0v = *(const s8*)&chs[(0 * 32 + bl) * 136 + e0];
        s8 c1v = *(const s8*)&chs[(1 * 32 + bl) * 136 + e0];
        s8 c2v = *(const s8*)&chs[(2 * 32 + bl) * 136 + e0];
        s8 c3v = *(const s8*)&chs[(3 * 32 + bl) * 136 + e0];
        ushort_t ov[8], mv[8];
        #pragma unroll
        for (int j = 0; j < 8; ++j) {
            float x0 = b2f((ushort_t)c0v[j]), x1 = b2f((ushort_t)c1v[j]);
            float x2 = b2f((ushort_t)c2v[j]), x3 = b2f((ushort_t)c3v[j]);
            ov[j] = f2b(a0 * x0 + a1 * x1 + a2 * x2 + a3 * x3);
            mv[j] = f2b(fmaxf(fmaxf(x0, x1), fmaxf(x2, x3)));   // exact on bf16
        }
        size_t ro = (size_t)(pbase + bl) * 128 + e0;
        *(s8*)(h0out + ro) = *(const s8*)ov;
        *(s8*)(pmaxs + ro) = *(const s8*)mv;
    }
}

// ---------------------------------------------------------------------------
// Fused level step for tiny tail levels (round-6 body, verified correct).
// MODE 1: GRU+attn+max; MODE 2: root GRU -> pmax slot. 64 child rows/block.
// Launched PER LEVEL (in-kernel grid barriers measured catastrophic: cross-XCD
// acquire-spin = L2 invalidate storm, 185 µs idle — round 7).
// ---------------------------------------------------------------------------
template <int MODE>
__global__ __launch_bounds__(512, 2) void level_small(
    const int* __restrict__ tokens, const ushort_t* __restrict__ embb,
    const ushort_t* __restrict__ wihb, const ushort_t* __restrict__ whhb,
    const float* __restrict__ bih, const float* __restrict__ bhh,
    const ushort_t* __restrict__ swtb, const float* __restrict__ sbv,
    const float* __restrict__ cwv,
    const ushort_t* __restrict__ h0in, ushort_t* __restrict__ h0out,
    ushort_t* __restrict__ pmaxs, int tok_start)
{
    constexpr bool ATTN = (MODE != 2);

    __shared__ ushort_t xs[64 * 136];
    __shared__ ushort_t hs[64 * 136];
    __shared__ float scp[8][64];
    __shared__ float sc[64];
    __shared__ float al[4][16];

    const int t = threadIdx.x;
    const int p = (int)(blockIdx.x >> 4);
    const int y = (int)(blockIdx.x & 15);

    {
        int lr = t >> 3, ci = (t & 7) * 16;
        int node, b;
        if (ATTN) { node = 4 * p + (lr >> 4); b = y * 16 + (lr & 15); }
        else      { node = 0;                 b = y * 64 + lr; }
        int tok = tokens[(tok_start + node) * 256 + b];
        const ushort_t* src = embb + (size_t)tok * 128 + ci;
        ushort_t* dst = &xs[lr * 136 + ci];
        *(s8*)dst       = *(const s8*)src;
        *(s8*)(dst + 8) = *(const s8*)(src + 8);
        const ushort_t* hsrc = h0in + ((size_t)node * 256 + b) * 128 + ci;
        ushort_t* hdst = &hs[lr * 136 + ci];
        *(s8*)hdst       = *(const s8*)hsrc;
        *(s8*)(hdst + 8) = *(const s8*)(hsrc + 8);
    }

    const int lane = t & 63, w = t >> 6;
    const int quad = lane >> 4, l15 = lane & 15;
    const int gA = w * 16 + l15;
    const int g0 = w * 16 + quad * 4;

    s8 bwi[3][4], bwh[3][4];
    #pragma unroll
    for (int gm = 0; gm < 3; ++gm) {
        const ushort_t* wp = wihb + (size_t)(gm * 128 + gA) * 128 + quad * 8;
        #pragma unroll
        for (int s = 0; s < 4; ++s) bwi[gm][s] = *(const s8*)(wp + 32 * s);
        const ushort_t* wp2 = whhb + (size_t)(gm * 128 + gA) * 128 + quad * 8;
        #pragma unroll
        for (int s = 0; s < 4; ++s) bwh[gm][s] = *(const s8*)(wp2 + 32 * s);
    }

    f4 cR0, cZ0, cN0, cNh0;
    {
        float4 a = *(const float4*)(bih + g0);
        float4 b = *(const float4*)(bhh + g0);
        cR0[0] = a.x + b.x; cR0[1] = a.y + b.y; cR0[2] = a.z + b.z; cR0[3] = a.w + b.w;
        float4 c = *(const float4*)(bih + 128 + g0);
        float4 d = *(const float4*)(bhh + 128 + g0);
        cZ0[0] = c.x + d.x; cZ0[1] = c.y + d.y; cZ0[2] = c.z + d.z; cZ0[3] = c.w + d.w;
        float4 e = *(const float4*)(bih + 256 + g0);
        float4 f = *(const float4*)(bhh + 256 + g0);
        cN0[0] = e.x; cN0[1] = e.y; cN0[2] = e.z; cN0[3] = e.w;
        cNh0[0] = f.x; cNh0[1] = f.y; cNh0[2] = f.z; cNh0[3] = f.w;
    }

    __syncthreads();

    #pragma unroll 1
    for (int mt = 0; mt < 4; ++mt) {
        const int row = mt * 16 + l15;
        s8 ax[4], ah[4];
        {
            const ushort_t* ap = &xs[row * 136 + quad * 8];
            #pragma unroll
            for (int s = 0; s < 4; ++s) ax[s] = *(const s8*)(ap + 32 * s);
            const ushort_t* hp = &hs[row * 136 + quad * 8];
            #pragma unroll
            for (int s = 0; s < 4; ++s) ah[s] = *(const s8*)(hp + 32 * s);
        }

        f4 accR = cR0, accZ = cZ0, accN = cN0, accNh = cNh0;
        #pragma unroll
        for (int s = 0; s < 4; ++s) {
            accR = __builtin_amdgcn_mfma_f32_16x16x32_bf16(bwi[0][s], ax[s], accR, 0, 0, 0);
            accZ = __builtin_amdgcn_mfma_f32_16x16x32_bf16(bwi[1][s], ax[s], accZ, 0, 0, 0);
            accN = __builtin_amdgcn_mfma_f32_16x16x32_bf16(bwi[2][s], ax[s], accN, 0, 0, 0);
        }
        #pragma unroll
        for (int s = 0; s < 4; ++s) {
            accR  = __builtin_amdgcn_mfma_f32_16x16x32_bf16(bwh[0][s], ah[s], accR, 0, 0, 0);
            accZ  = __builtin_amdgcn_mfma_f32_16x16x32_bf16(bwh[1][s], ah[s], accZ, 0, 0, 0);
            accNh = __builtin_amdgcn_mfma_f32_16x16x32_bf16(bwh[2][s], ah[s], accNh, 0, 0, 0);
        }

        __syncthreads();   // tile mt reads done -> safe to overwrite xs

        float h0v[4];
        {
            short4 h04 = *(const short4*)&hs[row * 136 + g0];
            h0v[0] = b2f((ushort_t)h04.x); h0v[1] = b2f((ushort_t)h04.y);
            h0v[2] = b2f((ushort_t)h04.z); h0v[3] = b2f((ushort_t)h04.w);
        }
        ushort_t ov[4];
        #pragma unroll
        for (int r = 0; r < 4; ++r) {
            float rr = sigf(accR[r]);
            float zz = sigf(accZ[r]);
            float nn = tanh_f(accN[r] + rr * accNh[r]);
            float h = nn + zz * (h0v[r] - nn);
            ov[r] = f2b(h);
        }
        *(short4*)&xs[row * 136 + g0] = *(const short4*)ov;
    }
    __syncthreads();

    if (MODE == 2) {
        int row = t >> 3, ci = (t & 7) * 16;
        ushort_t* d = pmaxs + ((size_t)(y * 64 + row)) * 128 + ci;
        const ushort_t* s_ = &xs[row * 136 + ci];
        *(s8*)d       = *(const s8*)s_;
        *(s8*)(d + 8) = *(const s8*)(s_ + 8);
        return;
    }

    // attention over the 4 siblings
    s8 bsw[4];
    {
        const ushort_t* wp = swtb + (size_t)gA * 128 + quad * 8;
        #pragma unroll
        for (int s = 0; s < 4; ++s) bsw[s] = *(const s8*)(wp + 32 * s);
    }
    f4 sb0;
    float cw4[4];
    {
        float4 a = *(const float4*)(sbv + g0);
        sb0[0] = a.x; sb0[1] = a.y; sb0[2] = a.z; sb0[3] = a.w;
        float4 b = *(const float4*)(cwv + g0);
        cw4[0] = b.x; cw4[1] = b.y; cw4[2] = b.z; cw4[3] = b.w;
    }

    #pragma unroll 1
    for (int mt = 0; mt < 4; ++mt) {
        const int crow = mt * 16 + l15;
        s8 a[4];
        const ushort_t* ap = &xs[crow * 136 + quad * 8];
        #pragma unroll
        for (int s = 0; s < 4; ++s) a[s] = *(const s8*)(ap + 32 * s);

        f4 acc = sb0;
        #pragma unroll
        for (int s = 0; s < 4; ++s)
            acc = __builtin_amdgcn_mfma_f32_16x16x32_bf16(bsw[s], a[s], acc, 0, 0, 0);

        float part = 0.f;
        #pragma unroll
        for (int r = 0; r < 4; ++r)
            part += tanh_f(acc[r]) * cw4[r];
        part += __shfl_xor(part, 16);
        part += __shfl_xor(part, 32);
        if (quad == 0) scp[w][crow] = part;
    }
    __syncthreads();

    if (t < 64) {
        float s_ = 0.f;
        #pragma unroll
        for (int ww = 0; ww < 8; ++ww) s_ += scp[ww][t];
        sc[t] = tanh_f(s_);
    }
    __syncthreads();

    if (t < 16) {
        float s0 = sc[t], s1 = sc[16 + t], s2 = sc[32 + t], s3 = sc[48 + t];
        float m = fmaxf(fmaxf(s0, s1), fmaxf(s2, s3));
        float e0 = fexp2f((s0 - m) * 1.44269504f), e1 = fexp2f((s1 - m) * 1.44269504f);
        float e2 = fexp2f((s2 - m) * 1.44269504f), e3 = fexp2f((s3 - m) * 1.44269504f);
        float inv = frcpf(e0 + e1 + e2 + e3);
        al[0][t] = e0 * inv; al[1][t] = e1 * inv; al[2][t] = e2 * inv; al[3][t] = e3 * inv;
    }
    __syncthreads();

    if (t < 256) {
        int bl = t >> 4, e0 = (t & 15) * 8;
        float a0 = al[0][bl], a1 = al[1][bl], a2 = al[2][bl], a3 = al[3][bl];
        s8 c0 = *(const s8*)&xs[(0 * 16 + bl) * 136 + e0];
        s8 c1 = *(const s8*)&xs[(1 * 16 + bl) * 136 + e0];
        s8 c2 = *(const s8*)&xs[(2 * 16 + bl) * 136 + e0];
        s8 c3 = *(const s8*)&xs[(3 * 16 + bl) * 136 + e0];
        ushort_t ov[8];
        #pragma unroll
        for (int j = 0; j < 8; ++j) {
            float v = a0 * b2f((ushort_t)c0[j]) + a1 * b2f((ushort_t)c1[j])
                    + a2 * b2f((ushort_t)c2[j]) + a3 * b2f((ushort_t)c3[j]);
            ov[j] = f2b(v);
        }
        *(s8*)(h0out + ((size_t)p * 256 + y * 16 + bl) * 128 + e0) = *(const s8*)ov;
    } else {
        int tt = t - 256;
        int bl = tt >> 4, e0 = (tt & 15) * 8;
        s8 c0 = *(const s8*)&xs[(0 * 16 + bl) * 136 + e0];
        s8 c1 = *(const s8*)&xs[(1 * 16 + bl) * 136 + e0];
        s8 c2 = *(const s8*)&xs[(2 * 16 + bl) * 136 + e0];
        s8 c3 = *(const s8*)&xs[(3 * 16 + bl) * 136 + e0];
        ushort_t ov[8];
        #pragma unroll
        for (int j = 0; j < 8; ++j) {
            float v = fmaxf(fmaxf(b2f((ushort_t)c0[j]), b2f((ushort_t)c1[j])),
                            fmaxf(b2f((ushort_t)c2[j]), b2f((ushort_t)c3[j])));
            ov[j] = f2b(v);
        }
        *(s8*)(pmaxs + (size_t)p * 32768 + (size_t)(y * 16 + bl) * 128 + e0) = *(const s8*)ov;
    }
}

// ---------------------------------------------------------------------------
// Two-stage final max over 342 bf16 slots, vectorized s8 loads.
// Stage 1: grid (16, 8) — chunk y covers 43 slots -> fp32 partial pm2[y].
// Stage 2: 16 blocks — max over 8 partials -> out.
// ---------------------------------------------------------------------------
#define N_SLOTS 342
__global__ __launch_bounds__(256) void max_stage1(
    const ushort_t* __restrict__ pmax, float* __restrict__ pm2)
{
    int e0 = (blockIdx.x * 256 + threadIdx.x) * 8;   // 0..32760
    int y = blockIdx.y;
    int s0 = y * 43, s1 = min(N_SLOTS, s0 + 43);
    float v[8];
    #pragma unroll
    for (int j = 0; j < 8; ++j) v[j] = -INFINITY;
    for (int s = s0; s < s1; ++s) {
        s8 c = *(const s8*)(pmax + (size_t)s * 32768 + e0);
        #pragma unroll
        for (int j = 0; j < 8; ++j) v[j] = fmaxf(v[j], b2f((ushort_t)c[j]));
    }
    float* p = pm2 + (size_t)y * 32768 + e0;
    #pragma unroll
    for (int j = 0; j < 8; ++j) p[j] = v[j];
}

__global__ __launch_bounds__(256) void max_stage2(
    const float* __restrict__ pm2, float* __restrict__ out)
{
    int e0 = (blockIdx.x * 256 + threadIdx.x) * 8;
    float v[8];
    {
        float4 a = *(const float4*)(pm2 + e0);
        float4 b = *(const float4*)(pm2 + e0 + 4);
        v[0] = a.x; v[1] = a.y; v[2] = a.z; v[3] = a.w;
        v[4] = b.x; v[5] = b.y; v[6] = b.z; v[7] = b.w;
    }
    #pragma unroll
    for (int y = 1; y < 8; ++y) {
        float4 a = *(const float4*)(pm2 + (size_t)y * 32768 + e0);
        float4 b = *(const float4*)(pm2 + (size_t)y * 32768 + e0 + 4);
        v[0] = fmaxf(v[0], a.x); v[1] = fmaxf(v[1], a.y);
        v[2] = fmaxf(v[2], a.z); v[3] = fmaxf(v[3], a.w);
        v[4] = fmaxf(v[4], b.x); v[5] = fmaxf(v[5], b.y);
        v[6] = fmaxf(v[6], b.z); v[7] = fmaxf(v[7], b.w);
    }
    *(float4*)(out + e0)     = make_float4(v[0], v[1], v[2], v[3]);
    *(float4*)(out + e0 + 4) = make_float4(v[4], v[5], v[6], v[7]);
}

extern "C" void kernel_launch(void* const* d_in, const int* in_sizes, int n_in,
                              void* d_out, int out_size, void* d_ws, size_t ws_size,
                              hipStream_t stream)
{
    const int*   tokens = (const int*)d_in[0];
    const float* emb    = (const float*)d_in[1];
    const float* Wih    = (const float*)d_in[2];
    const float* Whh    = (const float*)d_in[3];
    const float* bih    = (const float*)d_in[4];
    const float* bhh    = (const float*)d_in[5];
    const float* SW     = (const float*)d_in[6];
    const float* sb     = (const float*)d_in[7];
    const float* cw     = (const float*)d_in[8];
    float* out = (float*)d_out;

    // ws layout (shorts unless noted)
    ushort_t* embb = (ushort_t*)d_ws;                        // 12.8 MB
    ushort_t* wihb = embb + (size_t)EMB_N;
    ushort_t* whhb = wihb + W_N;
    ushort_t* swtb = whhb + W_N;
    ushort_t* h5   = swtb + SW_N;                            // 1024n: 67.1 MB
    ushort_t* h4   = h5 + (size_t)1024 * 32768;              // 256n: 16.8 MB
    ushort_t* h0_4 = h4 + (size_t)256 * 32768;               // 256n
    ushort_t* h0_3 = h0_4 + (size_t)256 * 32768;             // 64n
    ushort_t* h0_2 = h0_3 + (size_t)64 * 32768;              // 16n
    ushort_t* h0_1 = h0_2 + (size_t)16 * 32768;              // 4n
    ushort_t* h0_0 = h0_1 + (size_t)4 * 32768;               // 1n
    ushort_t* pmax = h0_0 + (size_t)1 * 32768;               // 342 slots: 22.4 MB
    float*    pm2  = (float*)(pmax + (size_t)N_SLOTS * 32768); // 8*32768 f32: 1 MB

    // pmax slots: L5-max: 0..255 | L4: 256..319 | L3: 320..335 | L2: 336..339
    //             L1: 340 | root-h: 341

    cvt_kernel<<<(CVT_N / 4 + 255) / 256, 256, 0, stream>>>(
        emb, Wih, Whh, SW, embb, wihb, whhb, swtb);

    // L5 leaf GRU (1024 nodes): 262144 rows
    gru_mfma<false><<<2048, 512, 0, stream>>>(
        tokens, embb, wihb, whhb, bih, bhh, nullptr, h5, 341);
    // attn+max over h5 -> h0_4 + pmax[0..255] (65536 parent rows)
    attnmax_mfma<<<2048, 512, 0, stream>>>(h5, h0_4, pmax, swtb, sb, cw);

    // L4 GRU (256 nodes): 65536 rows
    gru_mfma<true><<<512, 512, 0, stream>>>(
        tokens, embb, wihb, whhb, bih, bhh, h0_4, h4, 85);
    // attn+max over h4 -> h0_3 + pmax[256..319] (16384 parent rows)
    attnmax_mfma<<<512, 512, 0, stream>>>(h4, h0_3, pmax + (size_t)256 * 32768,
                                          swtb, sb, cw);

    // tail levels as small launches (p = blk>>4, y = blk&15)
    level_small<1><<<256, 512, 0, stream>>>(    // L3: 64 nodes -> h0_2 + pmax[320..335]
        tokens, embb, wihb, whhb, bih, bhh, swtb, sb, cw,
        h0_3, h0_2, pmax + (size_t)320 * 32768, 21);
    level_small<1><<<64, 512, 0, stream>>>(     // L2: 16 nodes -> h0_1 + pmax[336..339]
        tokens, embb, wihb, whhb, bih, bhh, swtb, sb, cw,
        h0_2, h0_1, pmax + (size_t)336 * 32768, 5);
    level_small<1><<<16, 512, 0, stream>>>(     // L1: 4 nodes -> h0_0 + pmax[340]
        tokens, embb, wihb, whhb, bih, bhh, swtb, sb, cw,
        h0_1, h0_0, pmax + (size_t)340 * 32768, 1);
    level_small<2><<<4, 512, 0, stream>>>(      // root: GRU only -> pmax[341]
        tokens, embb, wihb, whhb, bih, bhh, swtb, sb, cw,
        h0_0, nullptr, pmax + (size_t)341 * 32768, 0);

    max_stage1<<<dim3(16, 8), 256, 0, stream>>>(pmax, pm2);
    max_stage2<<<16, 256, 0, stream>>>(pm2, out);
}